// Round 8
// baseline (1163.664 us; speedup 1.0000x reference)
//
// HierarchicalPattern — rev15. R14 post-mortem: spill fixed (FETCH 3.46 GB ->
// 25 MB, tell matched) but mask SLOWER: 842 µs at 2.15 GB = 2.5 TB/s — far
// below cache BW -> latency-bound, not BW-bound. Cause: 1-2 float4 in flight
// per thread; deeper reg prefetch is blocked by the ~50-f32 spill wall
// (R8/R12/R13). Fix: global_load_lds double-buffer — load depth lives in LDS,
// not VGPRs. 2 bufs x 2 planes (32 KB), 2 gload_lds(16B)/wave/chunk, RAW
// s_barrier + counted vmcnt(2) (T4 — __syncthreads would drain the queue).
// Per chunk: compute -> lgkmcnt(0) -> bar -> issue t+2 -> vmcnt(2) -> bar.
// Staggered chunk order decorrelates L2 bursts. acc stays 32-f32 (clean
// shape); kv = 4 regs, no prefetch regs. Phase 2 / output R14-verified,
// untouched. feat byte-identical. Residual diagnostic: if mask hits ~250-330,
// a real ~250 µs feat MUST surface in top-5 (free localization).
#include <hip/hip_runtime.h>
#include <hip/hip_fp16.h>
#include <cstdint>

#define SEQ 4096
#define NB 4
#define DMODEL 1024
#define ID 64
#define LW 16
#define GK 32
#define TQ 8

#define NEG_INF (-__builtin_inff())
#define MASKED4 0xFBFFFBFFu
#define FMAT (NB * SEQ * ID)          // floats per feature matrix (4 MiB)

typedef _Float16 f16x8 __attribute__((ext_vector_type(8)));
typedef float f32x4 __attribute__((ext_vector_type(4)));

// ---------------- Kernel 1: lf + gfT via MFMA (fp16 in, f32 out) -------------
// UNCHANGED from rev14 (isolation). grid 1024 x 512thr; wave w: half=w&1,
// ch=w>>1 (16-col quarter). D-layout col=l&15, row=(l>>4)*4+reg (verified).
__global__ __launch_bounds__(512)
void hp_feat_v14(const unsigned short* __restrict__ xu,
                 const unsigned short* __restrict__ Wlu,
                 const unsigned short* __restrict__ Wgu,
                 float* __restrict__ lf, float* __restrict__ gfT)
{
    const int tid = threadIdx.x;
    const int lane = tid & 63, w = tid >> 6;      // 8 waves
    const long row0 = (long)blockIdx.x * 16;
    const int half = w & 1;
    const int ch = w >> 1;                        // 0..3, 16 cols each
    const _Float16* xp = (const _Float16*)xu;
    const _Float16* Wp = (const _Float16*)(half ? Wgu : Wlu);

    const int lr = lane & 15;          // row-in-tile (A) / col-in-tile (B,D)
    const int kg = lane >> 4;          // k-group: k offset kg*8

    const _Float16* ap = xp + (row0 + lr) * DMODEL + kg * 8;
    const _Float16* bp = Wp + (long)(ch * 16 + lr) * DMODEL + kg * 8;

    f32x4 acc = (f32x4){0.f, 0.f, 0.f, 0.f};

#pragma unroll 4
    for (int k0 = 0; k0 < DMODEL; k0 += 32) {
        f16x8 av = *(const f16x8*)(ap + k0);
        f16x8 bv = *(const f16x8*)(bp + k0);
        acc = __builtin_amdgcn_mfma_f32_16x16x32_f16(av, bv, acc, 0, 0, 0);
    }

    if (!half) {        // lf[s][d]: 16 lanes = 16 consecutive d
#pragma unroll
        for (int r = 0; r < 4; r++)
            lf[(row0 + kg * 4 + r) * ID + ch * 16 + lr] = acc[r];
    } else {            // gfT[b][d][s]: float4 along s
        const int bb = (int)(row0 >> 12), s0 = (int)(row0 & 4095);
        float4 st = make_float4(acc[0], acc[1], acc[2], acc[3]);
        *(float4*)(gfT + ((long)bb * ID + ch * 16 + lr) * SEQ + s0 + kg * 4) = st;
    }
}

// ---------------- Kernel 2: 1024 threads, TQ=8, 4 keys/thread ----------------
// Phase 1 = gload_lds double-buffered pipeline (2 bufs x 2 planes x 16 KB).
// Raw s_barrier + counted vmcnt keeps 2 chunks in flight across barriers.
// Phase 2: float-domain bisection (R9-R14 verified), bitmap output (R8).
__global__ __launch_bounds__(1024, 4)
void hp_mask_v15(const float* __restrict__ lf, const float* __restrict__ gfT,
                 unsigned short* __restrict__ out)
{
    __shared__ float kstage[2][2 * SEQ];          // 64 KiB: [buf][plane*4096+s]
    __shared__ float qvT[ID][TQ];                 // [d][qi], 2 KiB
    __shared__ float lq[TQ][ID];                  // 2 KiB
    __shared__ unsigned long long redA[4][16];    // buf0,buf1,greater,equal
    __shared__ unsigned long long redB[4][16];    // (qi 0-3 in A, 4-7 in B)
    __shared__ unsigned int bitmap[TQ][SEQ / 32]; // 4 KiB selection bitmap
    __shared__ float lsc[TQ][LW];
    __shared__ unsigned char tm[1024];            // rare tie path: 4 keys/thr

    const int tid = threadIdx.x;
    const int lane = tid & 63, w = tid >> 6;      // 16 waves
    const int bid = blockIdx.x;                   // 2048 blocks
    const int xcd = bid & 7;
    const int b = xcd >> 1;                       // batch pinned to XCD pair
    const int qg = ((bid >> 3) << 1) | (xcd & 1); // 0..511
    const int q0 = qg * TQ;
    const float* gTb = gfT + (long)b * ID * SEQ;
    const float* lfb = lf + (long)b * SEQ * ID;
    const int c0 = (bid >> 3) & 31;               // stagger chunk start

    if (tid < 512) {   // qvT[d][qi] = gfT[b][d][q0+qi]; lq from lf rows
        int d = tid >> 3, qi = tid & 7;
        qvT[d][qi] = gTb[(long)d * SEQ + q0 + qi];
        int qi2 = tid >> 6, d2 = tid & 63;
        lq[qi2][d2] = lfb[(long)(q0 + qi2) * ID + d2];
    }
    ((unsigned int*)bitmap)[tid] = 0u;            // 1024 words exactly

    // stage chunks: chunk logical index tc covers planes {2*ch, 2*ch+1},
    // ch = (c0+tc)&31. Each wave loads segs {2w, 2w+1} (1 KB each) direct
    // to LDS. Per-lane global addr; wave-uniform LDS base (+lane*16 by HW).
    auto stage = [&](int tc, int bufi) {
        const int ch = (c0 + tc) & 31;
        const float* gsrc = gTb + (long)ch * 2 * SEQ;
#pragma unroll
        for (int i = 0; i < 2; ++i) {
            const int seg = w * 2 + i;            // 0..31
            const float* gp = gsrc + seg * 256 + lane * 4;
            float* lp = &kstage[bufi][seg * 256];
            __builtin_amdgcn_global_load_lds(
                (const __attribute__((address_space(1))) void*)gp,
                (__attribute__((address_space(3))) void*)lp, 16, 0, 0);
        }
    };

    // ---- Phase 1: pipelined scores ------------------------------------------
    float acc[4][TQ];                     // [j][qi] = 32 f32 (proven clean)
#pragma unroll
    for (int j = 0; j < 4; j++)
#pragma unroll
        for (int qi = 0; qi < TQ; qi++) acc[j][qi] = 0.f;

    stage(0, 0);
    stage(1, 1);
    asm volatile("s_waitcnt vmcnt(2)" ::: "memory");  // chunk 0 landed
    __builtin_amdgcn_s_barrier();                     // publish c0 + qvT/lq

#pragma unroll 1
    for (int t = 0; t < 32; ++t) {
        const int cur = t & 1;
        const int ch = (c0 + t) & 31;
#pragma unroll
        for (int p = 0; p < 2; ++p) {
            const int d = 2 * ch + p;
            const float4 kv = *(const float4*)&kstage[cur][p * SEQ + tid * 4];
            const float4 qlo = *(const float4*)&qvT[d][0];   // uniform b128
            const float4 qhi = *(const float4*)&qvT[d][4];
            float qds[8];
            qds[0] = qlo.x; qds[1] = qlo.y; qds[2] = qlo.z; qds[3] = qlo.w;
            qds[4] = qhi.x; qds[5] = qhi.y; qds[6] = qhi.z; qds[7] = qhi.w;
#pragma unroll
            for (int qi = 0; qi < TQ; qi++) {
                acc[0][qi] = fmaf(kv.x, qds[qi], acc[0][qi]);
                acc[1][qi] = fmaf(kv.y, qds[qi], acc[1][qi]);
                acc[2][qi] = fmaf(kv.z, qds[qi], acc[2][qi]);
                acc[3][qi] = fmaf(kv.w, qds[qi], acc[3][qi]);
            }
        }
        asm volatile("s_waitcnt lgkmcnt(0)" ::: "memory"); // my LDS reads done
        __builtin_amdgcn_s_barrier();          // all waves done reading cur
        if (t + 2 < 32) {
            stage(t + 2, cur);                 // refill just-freed buffer
            asm volatile("s_waitcnt vmcnt(2)" ::: "memory"); // c_{t+1} landed
        } else {
            asm volatile("s_waitcnt vmcnt(0)" ::: "memory");
        }
        __builtin_amdgcn_s_barrier();          // publish c_{t+1}
    }

    // ---- Phase 2a: in-place keys: sv = banned ? -1 : relu(s) ----------------
#pragma unroll
    for (int j = 0; j < 4; j++) {
        const int k = 4 * tid + j;
#pragma unroll
        for (int qi = 0; qi < TQ; qi++) {
            const int q = q0 + qi;
            const bool banned = (k <= q) && (k >= q - (LW - 1));
            acc[j][qi] = banned ? -1.0f : fmaxf(acc[j][qi], 0.f);
        }
    }

    // ---- Phase 2b: bisection for m32 in u-space, compares in float ----------
    // u = bits(sv)+1; u>=m <=> sv >= uint_as_float(m-1). 31 trials close
    // [0, 0x7F800000] to width <= 1; lo converges to m32 (R9-R14 verified).
    unsigned int lo[TQ], hi[TQ];
#pragma unroll
    for (int qi = 0; qi < TQ; qi++) { lo[qi] = 0u; hi[qi] = 0x7F800000u; }

#pragma unroll 1
    for (int it = 0; it < 31; ++it) {
        unsigned long long pcA = 0ull, pcB = 0ull;
#pragma unroll
        for (int qi = 0; qi < TQ; qi++) {
            const unsigned int mid = lo[qi] + ((hi[qi] - lo[qi]) >> 1);
            const float tf = __uint_as_float(mid - 1u);
            int cnt = 0;
#pragma unroll
            for (int j = 0; j < 4; j++)
                cnt += __popcll(__ballot(acc[j][qi] >= tf));
            if (qi < 4) pcA |= (unsigned long long)(unsigned int)cnt << (16 * qi);
            else        pcB |= (unsigned long long)(unsigned int)cnt << (16 * (qi - 4));
        }
        if (lane == 0) { redA[it & 1][w] = pcA; redB[it & 1][w] = pcB; }
        __syncthreads();
        unsigned long long totA = 0ull, totB = 0ull;
#pragma unroll
        for (int ww = 0; ww < 16; ww++) {
            totA += redA[it & 1][ww]; totB += redB[it & 1][ww];
        }
#pragma unroll
        for (int qi = 0; qi < TQ; qi++) {
            const unsigned int mid = lo[qi] + ((hi[qi] - lo[qi]) >> 1);
            const unsigned int cnt = (qi < 4)
                ? (unsigned int)((totA >> (16 * qi)) & 0xFFFFull)
                : (unsigned int)((totB >> (16 * (qi - 4))) & 0xFFFFull);
            if (cnt >= GK) lo[qi] = mid; else hi[qi] = mid;
        }
    }

    // ---- Phase 2c: C1 = #{u > m32}, T = #{u == m32} -------------------------
    int T[TQ], need[TQ];
    {
        unsigned long long pgA = 0ull, pgB = 0ull, peA = 0ull, peB = 0ull;
#pragma unroll
        for (int qi = 0; qi < TQ; qi++) {
            const float tg = __uint_as_float(lo[qi]);   // u>lo <=> sv>=float(lo)
            const unsigned int eb = lo[qi] - 1u;        // u==lo <=> bits(sv)==eb
            int cg = 0, ce = 0;
#pragma unroll
            for (int j = 0; j < 4; j++) {
                const float v = acc[j][qi];
                cg += __popcll(__ballot(v >= tg));
                ce += __popcll(__ballot(__float_as_uint(v) == eb));
            }
            if (qi < 4) {
                pgA |= (unsigned long long)(unsigned int)cg << (16 * qi);
                peA |= (unsigned long long)(unsigned int)ce << (16 * qi);
            } else {
                pgB |= (unsigned long long)(unsigned int)cg << (16 * (qi - 4));
                peB |= (unsigned long long)(unsigned int)ce << (16 * (qi - 4));
            }
        }
        if (lane == 0) {
            redA[2][w] = pgA; redA[3][w] = peA;
            redB[2][w] = pgB; redB[3][w] = peB;
        }
        __syncthreads();
        unsigned long long tgA = 0ull, teA = 0ull, tgB = 0ull, teB = 0ull;
#pragma unroll
        for (int ww = 0; ww < 16; ww++) {
            tgA += redA[2][ww]; teA += redA[3][ww];
            tgB += redB[2][ww]; teB += redB[3][ww];
        }
#pragma unroll
        for (int qi = 0; qi < TQ; qi++) {
            const int c1 = (qi < 4)
                ? (int)((tgA >> (16 * qi)) & 0xFFFFull)
                : (int)((tgB >> (16 * (qi - 4))) & 0xFFFFull);
            T[qi] = (qi < 4)
                ? (int)((teA >> (16 * qi)) & 0xFFFFull)
                : (int)((teB >> (16 * (qi - 4))) & 0xFFFFull);
            need[qi] = GK - c1;               // >= 1; T >= need guaranteed
        }
    }

    // ---- Phase 2d: mark selections in bitmap --------------------------------
#pragma unroll
    for (int qi = 0; qi < TQ; qi++) {
        const bool allties = (T[qi] == need[qi]);
        const float tg = __uint_as_float(lo[qi]);
        const unsigned int eb = lo[qi] - 1u;
#pragma unroll
        for (int j = 0; j < 4; j++) {
            const float v = acc[j][qi];
            const bool sel_ = (v >= tg)
                            | (allties & (__float_as_uint(v) == eb));
            if (sel_) {
                const int k = 4 * tid + j;
                atomicOr(&bitmap[qi][k >> 5], 1u << (k & 31));
            }
        }
    }

    // Rare exact-tie path: pick the `need` smallest-k ties ascending
    // (k = 4t + j increases lexicographically in (t, j)).
#pragma unroll 1
    for (int qi = 0; qi < TQ; qi++) {
        if (T[qi] > need[qi]) {           // block-uniform (T,need from shared)
            const unsigned int eb = lo[qi] - 1u;
            unsigned int m4 = 0u;
#pragma unroll
            for (int j = 0; j < 4; j++)
                if (__float_as_uint(acc[j][qi]) == eb) m4 |= 1u << j;
            tm[tid] = (unsigned char)m4;
            __syncthreads();
            if (tid == 0) {
                int taken = 0;
                for (int t = 0; t < 1024 && taken < need[qi]; t++) {
                    const unsigned int nib = tm[t];
                    for (int j = 0; j < 4 && taken < need[qi]; j++)
                        if ((nib >> j) & 1u) {
                            const int k = 4 * t + j;
                            atomicOr(&bitmap[qi][k >> 5], 1u << (k & 31));
                            taken++;
                        }
                }
            }
            __syncthreads();
        }
    }

    // ---- local window: 16 scores per query, stable top-ks -> bitmap ---------
    if (tid < TQ * LW) {                  // 128 threads
        int qi = tid >> 4, wnd = tid & 15;
        int q = q0 + qi;
        int win = q - (LW - 1) + wnd;
        float v = NEG_INF;
        if (win >= 0) {
            const float4* kr = (const float4*)(lfb + (long)win * ID);
            float s = 0.f;
#pragma unroll
            for (int d = 0; d < 16; d++) {
                float4 kvv = kr[d];
                const float4 qd = *(const float4*)&lq[qi][d * 4];
                s = fmaf(kvv.x, qd.x, s); s = fmaf(kvv.y, qd.y, s);
                s = fmaf(kvv.z, qd.z, s); s = fmaf(kvv.w, qd.w, s);
            }
            v = fmaxf(s, 0.f);
        }
        lsc[qi][wnd] = v;
    }
    __syncthreads();
    if (tid < TQ) {
        int qi = tid, q = q0 + qi;
        int L = (q + 1 < LW) ? q + 1 : LW;
        int ks = L / 5; if (ks < 1) ks = 1;   // == max(1, int(L*0.2))
        for (int t = 0; t < ks; t++) {
            float best = NEG_INF; int bi = 0;
            for (int wnd = 0; wnd < LW; wnd++) {
                float v = lsc[qi][wnd];
                if (v > best) { best = v; bi = wnd; }  // strict > keeps lowest idx
            }
            lsc[qi][bi] = NEG_INF;
            const int win = q - (LW - 1) + bi;
            atomicOr(&bitmap[qi][win >> 5], 1u << (win & 31));
        }
    }
    __syncthreads();

    // ---- output: single-pass fill from bitmap (each line written once) ------
    uint4* orow = (uint4*)(out + ((long)b * SEQ + q0) * SEQ);
#pragma unroll
    for (int i = 0; i < TQ * SEQ / 8 / 1024; i++) {  // 4 iters, 4096 uint4
        const int li = i * 1024 + tid;
        const int qi = li >> 9;          // 512 uint4 per row
        const int w8 = li & 511;         // cols 8*w8 .. 8*w8+7
        const unsigned int bits =
            (bitmap[qi][w8 >> 2] >> ((w8 & 3) * 8)) & 0xFFu;
        uint4 v;
        v.x = MASKED4 & ~(((bits &   1u) ? 0x0000FFFFu : 0u) |
                          ((bits &   2u) ? 0xFFFF0000u : 0u));
        v.y = MASKED4 & ~(((bits &   4u) ? 0x0000FFFFu : 0u) |
                          ((bits &   8u) ? 0xFFFF0000u : 0u));
        v.z = MASKED4 & ~(((bits &  16u) ? 0x0000FFFFu : 0u) |
                          ((bits &  32u) ? 0xFFFF0000u : 0u));
        v.w = MASKED4 & ~(((bits &  64u) ? 0x0000FFFFu : 0u) |
                          ((bits & 128u) ? 0xFFFF0000u : 0u));
        orow[li] = v;
    }
}

extern "C" void kernel_launch(void* const* d_in, const int* in_sizes, int n_in,
                              void* d_out, int out_size, void* d_ws, size_t ws_size,
                              hipStream_t stream) {
    const unsigned short* x  = (const unsigned short*)d_in[0];
    const unsigned short* Wl = (const unsigned short*)d_in[1];
    // d_in[2] = W_medium: dead in the reference — skipped.
    const unsigned short* Wg = (const unsigned short*)d_in[3];
    unsigned short* out = (unsigned short*)d_out;

    float* lf  = (float*)d_ws;                        // 4 MiB, row-major
    float* gfT = lf + (long)FMAT;                     // 4 MiB, [b][d][s]

    hp_feat_v14<<<NB * SEQ / 16, 512, 0, stream>>>(x, Wl, Wg, lf, gfT);
    hp_mask_v15<<<NB * SEQ / TQ, 1024, 0, stream>>>(lf, gfT, out);
}